// Round 1
// baseline (221.105 us; speedup 1.0000x reference)
//
#include <hip/hip_runtime.h>

// Attention block: B=16, C=512, N=1024(=32x32), GROUPS=8, EPS=1e-5
//
// R7: all four GEMMs moved from the 128x128 2-phase loop (m97-class,
// ~23% MfmaUtil, barrier-drain bound) to the 256x256 8-phase schedule:
//   T1 XCD-aware block swizzle (kept from R4)
//   T2 LDS XOR swizzle (chunk ^= row&7) applied global-source-side +
//      ds_read-side (global_load_lds writes linearly)
//   T3/T4 8-phase interleave, counted vmcnt(4) at phases 4/8 only
//   T5 s_setprio(1) around each 16-MFMA cluster
// 512 thr / 8 waves (2Mx4N), per-wave 128x64 out, BK=64, LDS 128 KiB
// double-buffered. Prefetch ledger: prologue K0(A0,A1,B0,B1)+K1(B0,B1),
// vmcnt(4) -> K0 resident; steady state each stage-issue >= 1 barrier
// pair after target region's last read; tail prefetches clamp k->0.
//
// Layouts: hn_t[B][N][C], QKt[B][N][1024]=[Q|K], V[B][C][N],
//          expS bf16 [B][N][N], At[B][N][C] (aliases dead hn_t).

#define BATCH 16
#define CCH 512
#define NSP 1024
#define EPSV 1e-5f

typedef short bf16x8 __attribute__((ext_vector_type(8)));
typedef float f32x4 __attribute__((ext_vector_type(4)));

__device__ __forceinline__ unsigned short f2bf(float f) {
    unsigned int u = __float_as_uint(f);
    u += 0x7FFF + ((u >> 16) & 1);  // RNE
    return (unsigned short)(u >> 16);
}

__device__ __forceinline__ void glds16(const void* g, void* l) {
    __builtin_amdgcn_global_load_lds(
        (const __attribute__((address_space(1))) unsigned int*)g,
        (__attribute__((address_space(3))) unsigned int*)l, 16, 0, 0);
}

#define MEMF asm volatile("" ::: "memory")
#define VMW(n) asm volatile("s_waitcnt vmcnt(" #n ")" ::: "memory")
#define LGKM(n) asm volatile("s_waitcnt lgkmcnt(" #n ")" ::: "memory")
#define BAR_ACQ do { MEMF; __builtin_amdgcn_s_barrier(); LGKM(0); \
                     __builtin_amdgcn_s_setprio(1); } while (0)
#define BAR_REL do { __builtin_amdgcn_s_setprio(0); MEMF; \
                     __builtin_amdgcn_s_barrier(); } while (0)

// LDS map (shorts): A(buf,h) = buf*16384 + h*8192 ; B(buf,h) = 32768 + same.
// Half-tile = 128 rows x 64 k bf16, linear row-major (128 B/row); the T2
// swizzle permutes which global 16B chunk lands in each slot:
//   LDS slot (row, chunk j) holds global (row, j ^ (row&7)).
#define STG_A(cbuf, h, kk) do { \
    const unsigned short* p_ = Asrc + (size_t)((h) * 128) * astr + (kk); \
    glds16(p_, ldsW + (cbuf) * 16384 + (h) * 8192); \
    glds16(p_ + (size_t)64 * astr, ldsW + (cbuf) * 16384 + (h) * 8192 + 4096); \
  } while (0)
#define STG_B(cbuf, h, kk) do { \
    const unsigned short* p_ = Bsrc + (size_t)((h) * 128) * bstr + (kk); \
    glds16(p_, ldsW + 32768 + (cbuf) * 16384 + (h) * 8192); \
    glds16(p_ + (size_t)64 * bstr, ldsW + 32768 + (cbuf) * 16384 + (h) * 8192 + 4096); \
  } while (0)
#define LDA4(cbuf, mq) do { \
    _Pragma("unroll") for (int mi_ = 0; mi_ < 4; mi_++) { \
      const short* p_ = L + (cbuf) * 16384 + aRd + ((mq) * 4 + mi_) * 1024; \
      a[mi_][0] = *(const bf16x8*)(p_ + cA0); \
      a[mi_][1] = *(const bf16x8*)(p_ + cA1); } \
  } while (0)
#define LDB2(cbuf, nq, arr) do { \
    _Pragma("unroll") for (int ni_ = 0; ni_ < 2; ni_++) { \
      const short* p_ = L + (cbuf) * 16384 + bRd + ((nq) * 2 + ni_) * 1024; \
      arr[ni_][0] = *(const bf16x8*)(p_ + cA0); \
      arr[ni_][1] = *(const bf16x8*)(p_ + cA1); } \
  } while (0)
#define MMAQ(mq, nq, arr) do { \
    _Pragma("unroll") for (int mi_ = 0; mi_ < 4; mi_++) \
    _Pragma("unroll") for (int ni_ = 0; ni_ < 2; ni_++) { \
      const int ix_ = ((mq) * 4 + mi_) * 4 + (nq) * 2 + ni_; \
      acc[ix_] = __builtin_amdgcn_mfma_f32_16x16x32_bf16(a[mi_][0], arr[ni_][0], acc[ix_], 0, 0, 0); \
      acc[ix_] = __builtin_amdgcn_mfma_f32_16x16x32_bf16(a[mi_][1], arr[ni_][1], acc[ix_], 0, 0, 0); } \
  } while (0)

// NT GEMM: C[256x256] += A[256xK] * B[256xK]^T, both row-major over K.
__device__ __forceinline__ void gemm256_loop(
    const unsigned short* __restrict__ Ag, const unsigned short* __restrict__ Bg,
    int astr, int bstr, int ktot, short* L, f32x4* acc) {
    const int t = threadIdx.x;
    const int lane = t & 63, w = t >> 6;
    const int wm = w >> 2, wn = w & 3;          // wave grid 2(M) x 4(N)
    const int fr = lane & 15, fj = lane >> 4;
    const int rA = t >> 3;                       // staging row (8 chunks/row)
    const int jx = ((t & 7) ^ (rA & 7)) * 8;     // swizzled source chunk
    const unsigned short* Asrc = Ag + (size_t)rA * astr + jx;
    const unsigned short* Bsrc = Bg + (size_t)rA * bstr + jx;
    short* ldsW = L + w * 512;                   // wave-uniform LDS base
    const int aRd = wm * 8192 + fr * 64;
    const int bRd = 32768 + (wn >> 1) * 8192 + (wn & 1) * 4096 + fr * 64;
    const int cA0 = (fj ^ (fr & 7)) * 8;         // kk=0 swizzled col
    const int cA1 = ((4 + fj) ^ (fr & 7)) * 8;   // kk=1 swizzled col
    bf16x8 a[4][2], b01[2][2], b23[2][2];

    // prologue: K0 fully + K1.B; vmcnt(4) -> K0 resident, K1.B in flight
    STG_A(0, 0, 0); STG_A(0, 1, 0); STG_B(0, 0, 0); STG_B(0, 1, 0);
    STG_B(1, 0, 64); STG_B(1, 1, 64);
    VMW(4);
    MEMF; __builtin_amdgcn_s_barrier();

    for (int k0 = 0; k0 < ktot; k0 += 128) {
        const int kB1 = k0 + 64;                              // buf1 current A
        const int kN1 = (k0 + 128 < ktot) ? k0 + 128 : 0;     // buf0 next
        const int kN2 = (k0 + 192 < ktot) ? k0 + 192 : 0;     // buf1 next B
        // phase 1: Q00(buf0); stage buf1.A0
        LDA4(0, 0); LDB2(0, 0, b01);
        STG_A(1, 0, kB1);
        LGKM(8);
        BAR_ACQ; MMAQ(0, 0, b01); BAR_REL;
        // phase 2: Q01; stage buf1.A1
        LDB2(0, 1, b23);
        STG_A(1, 1, kB1);
        BAR_ACQ; MMAQ(0, 1, b23); BAR_REL;
        // phase 3: Q10; stage buf0.B0 (next) -- buf0.B reads done at p2
        LDA4(0, 1);
        STG_B(0, 0, kN1);
        BAR_ACQ; MMAQ(1, 0, b01); BAR_REL;
        // phase 4: Q11; stage buf0.B1; wait -> buf1 resident for p5
        STG_B(0, 1, kN1);
        VMW(4);
        BAR_ACQ; MMAQ(1, 1, b23); BAR_REL;
        // phase 5: Q00(buf1); stage buf0.A0 (next) -- buf0.A reads done at p3
        LDA4(1, 0); LDB2(1, 0, b01);
        STG_A(0, 0, kN1);
        LGKM(8);
        BAR_ACQ; MMAQ(0, 0, b01); BAR_REL;
        // phase 6: Q01; stage buf0.A1
        LDB2(1, 1, b23);
        STG_A(0, 1, kN1);
        BAR_ACQ; MMAQ(0, 1, b23); BAR_REL;
        // phase 7: Q10; stage buf1.B0 (next) -- buf1.B reads done at p6
        LDA4(1, 1);
        STG_B(1, 0, kN2);
        BAR_ACQ; MMAQ(1, 0, b01); BAR_REL;
        // phase 8: Q11; stage buf1.B1; wait -> buf0(next) resident for p1
        STG_B(1, 1, kN2);
        VMW(4);
        BAR_ACQ; MMAQ(1, 1, b23); BAR_REL;
    }
    VMW(0);  // drain tail (garbage) prefetches before epilogue/endpgm
}

#define ACC_INIT32(acc)                                      \
    f32x4 acc[32];                                           \
    _Pragma("unroll") for (int i = 0; i < 32; i++)           \
        acc[i] = (f32x4){0.f, 0.f, 0.f, 0.f};

#define EPI256()                                             \
    const int t = threadIdx.x, lane = t & 63, w8 = t >> 6;   \
    const int wr = (w8 >> 2) * 128, wc = (w8 & 3) * 64;      \
    const int fr = lane & 15, rr0 = (lane >> 4) * 4;

// -- setup: GN stats (0..127) + weight cvt (128..1151) + Lsum zero (1152..) --
__global__ __launch_bounds__(256) void setup_k(
    const float* __restrict__ x, float* __restrict__ stats,
    const float* __restrict__ wa, unsigned short* __restrict__ oa, int na4,
    const float* __restrict__ wb, unsigned short* __restrict__ ob, int nb4,
    float* __restrict__ Lsum) {
    const int t = threadIdx.x;
    if (blockIdx.x < 128) {
        const int bg = blockIdx.x;
        const float4* xp = (const float4*)(x + (size_t)bg * 65536);
        float s = 0.f, q = 0.f;
#pragma unroll
        for (int i = 0; i < 64; i++) {
            float4 v = xp[t + i * 256];
            s += v.x + v.y + v.z + v.w;
            q += v.x * v.x + v.y * v.y + v.z * v.z + v.w * v.w;
        }
#pragma unroll
        for (int off = 32; off; off >>= 1) {
            s += __shfl_down(s, off);
            q += __shfl_down(q, off);
        }
        __shared__ float rs[4], rq[4];
        const int wave = t >> 6, lane = t & 63;
        if (lane == 0) { rs[wave] = s; rq[wave] = q; }
        __syncthreads();
        if (t == 0) {
            float S = rs[0] + rs[1] + rs[2] + rs[3];
            float Q = rq[0] + rq[1] + rq[2] + rq[3];
            const float inv = 1.f / 65536.f;
            float mean = S * inv;
            float var = Q * inv - mean * mean;
            stats[bg * 2] = mean;
            stats[bg * 2 + 1] = rsqrtf(var + EPSV);
        }
    } else if (blockIdx.x < 1152) {
        int i = (blockIdx.x - 128) * 256 + t;
        const float* src;
        unsigned short* dst;
        int j;
        if (i < na4) { src = wa; dst = oa; j = i; }
        else { j = i - na4; if (j >= nb4) return; src = wb; dst = ob; }
        float4 v = ((const float4*)src)[j];
        ushort4 o;
        o.x = f2bf(v.x); o.y = f2bf(v.y); o.z = f2bf(v.z); o.w = f2bf(v.w);
        ((ushort4*)dst)[j] = o;
    } else {
        int i = (blockIdx.x - 1152) * 256 + t;  // 16 blocks x 256 float4
        ((float4*)Lsum)[i] = (float4){0.f, 0.f, 0.f, 0.f};
    }
}

// ---------------- GN normalize + transpose -> hn_t[B][N][C] bf16 --------
__global__ __launch_bounds__(256) void gn_tr_k(
    const float* __restrict__ x, const float* __restrict__ gamma,
    const float* __restrict__ beta, const float* __restrict__ stats,
    unsigned short* __restrict__ hn_t) {
    const int nt = blockIdx.x, ct = blockIdx.y, b = blockIdx.z;
    __shared__ __align__(16) unsigned short T[64 * 72];  // [n][c] +pad
    const int t = threadIdx.x;
    const float mean = stats[(b * 8 + ct) * 2];
    const float rstd = stats[(b * 8 + ct) * 2 + 1];
    const int cl = t >> 2, nc = t & 3;
    const int c = ct * 64 + cl;
    const float ga = gamma[c] * rstd;
    const float be = beta[c] - mean * ga;
    const float4* xp = (const float4*)(x + ((size_t)b * CCH + c) * NSP + nt * 64);
#pragma unroll
    for (int j = 0; j < 4; j++) {
        float4 v = xp[nc * 4 + j];
        int n = nc * 16 + j * 4;
        T[(n + 0) * 72 + cl] = f2bf(v.x * ga + be);
        T[(n + 1) * 72 + cl] = f2bf(v.y * ga + be);
        T[(n + 2) * 72 + cl] = f2bf(v.z * ga + be);
        T[(n + 3) * 72 + cl] = f2bf(v.w * ga + be);
    }
    __syncthreads();
    const int nl = t >> 2, cc = t & 3;
    unsigned short* dst = hn_t + ((size_t)b * NSP + nt * 64 + nl) * CCH + ct * 64 + cc * 16;
    const unsigned short* src = T + nl * 72 + cc * 16;
    *(uint4*)dst = *(const uint4*)src;
    *(uint4*)(dst + 8) = *(const uint4*)(src + 8);
}

// ---------------- QKV (merged): slot<16 -> Q|K rows, slot>=16 -> V ----------
// grid: 384 blocks x 512 thr; batch pinned to XCD (lin&7)
__global__ __launch_bounds__(512, 2) void gemm_qkv_k(
    const unsigned short* __restrict__ hn_t, const unsigned short* __restrict__ wq,
    const float* __restrict__ bq, unsigned short* __restrict__ QKt,
    unsigned short* __restrict__ Vb) {
    __shared__ __align__(16) short L[65536];  // 128 KiB
    const int lin = blockIdx.x, xcd = lin & 7;
    int slot = lin >> 3;                      // [0,48)
    const int hi = (slot >= 24) ? 1 : 0;
    const int b = xcd + 8 * hi;
    slot -= hi * 24;
    ACC_INIT32(acc);
    if (slot < 16) {
        const int mt = (slot & 3) * 256, nt = (slot >> 2) * 256;
        gemm256_loop(hn_t + ((size_t)b * NSP + mt) * CCH, wq + (size_t)nt * CCH,
                     CCH, CCH, CCH, L, acc);
        unsigned short* Ob = QKt + (size_t)b * NSP * 1024;
        EPI256();
#pragma unroll
        for (int ni = 0; ni < 4; ni++) {
            const int col = nt + wc + ni * 16 + fr;
            const float bias = bq[col];
#pragma unroll
            for (int mi = 0; mi < 8; mi++) {
                const int row = mt + wr + mi * 16 + rr0;
#pragma unroll
                for (int r = 0; r < 4; r++)
                    Ob[(size_t)(row + r) * 1024 + col] = f2bf(acc[mi * 4 + ni][r] + bias);
            }
        }
    } else {
        const int s2 = slot - 16;
        const int mt = (s2 & 1) * 256, nt = (s2 >> 1) * 256;
        gemm256_loop(wq + (size_t)(1024 + mt) * CCH,
                     hn_t + ((size_t)b * NSP + nt) * CCH, CCH, CCH, CCH, L, acc);
        unsigned short* Ob = Vb + (size_t)b * CCH * NSP;
        EPI256();
#pragma unroll
        for (int mi = 0; mi < 8; mi++) {
            const int row = mt + wr + mi * 16 + rr0;
#pragma unroll
            for (int r = 0; r < 4; r++) {
                const float bias = bq[1024 + row + r];
#pragma unroll
                for (int ni = 0; ni < 4; ni++) {
                    const int col = nt + wc + ni * 16 + fr;
                    Ob[(size_t)(row + r) * NSP + col] = f2bf(acc[mi * 4 + ni][r] + bias);
                }
            }
        }
    }
}

// ------- scores+exp: expS[b][n][m]=exp(scale*q.k) bf16; Lsum[b][n] += rowsum
// grid: 256 blocks x 512 thr
__global__ __launch_bounds__(512, 2) void gemm_scores_k(
    const unsigned short* __restrict__ QKt, unsigned short* __restrict__ expS,
    float* __restrict__ Lsum) {
    __shared__ __align__(16) short L[65536];
    const int lin = blockIdx.x, xcd = lin & 7;
    int slot = lin >> 3;                      // [0,32)
    const int hi = (slot >= 16) ? 1 : 0;
    const int b = xcd + 8 * hi;
    slot -= hi * 16;
    const int mt = (slot & 3) * 256, nt = (slot >> 2) * 256;
    const unsigned short* base = QKt + (size_t)b * NSP * 1024;
    ACC_INIT32(acc);
    gemm256_loop(base + (size_t)mt * 1024, base + (size_t)nt * 1024 + 512,
                 1024, 1024, 512, L, acc);
    unsigned short* Ob = expS + (size_t)b * NSP * NSP;
    float* Ls = Lsum + (size_t)b * NSP;
    const float scale = 0.044194173824159216f;  // 512^-0.5
    EPI256();
#pragma unroll
    for (int mi = 0; mi < 8; mi++) {
#pragma unroll
        for (int r = 0; r < 4; r++) {
            const int row = mt + wr + mi * 16 + rr0 + r;
            float rs = 0.f;
#pragma unroll
            for (int ni = 0; ni < 4; ni++) {
                const int col = nt + wc + ni * 16 + fr;
                float e = __expf(acc[mi * 4 + ni][r] * scale);
                Ob[(size_t)row * NSP + col] = f2bf(e);
                rs += e;
            }
            rs += __shfl_xor(rs, 1);
            rs += __shfl_xor(rs, 2);
            rs += __shfl_xor(rs, 4);
            rs += __shfl_xor(rs, 8);
            if (fr == 0) atomicAdd(&Ls[row], rs);
        }
    }
}

// ---------------- PV: At[b][n][c] = (expS[n][:] . V[c][:]) / Lsum[n] --------
// grid: 128 blocks x 512 thr
__global__ __launch_bounds__(512, 2) void gemm_pv_k(
    const unsigned short* __restrict__ expS, const unsigned short* __restrict__ Vb,
    const float* __restrict__ Lsum, unsigned short* __restrict__ At) {
    __shared__ __align__(16) short L[65536];
    const int lin = blockIdx.x, xcd = lin & 7;
    int slot = lin >> 3;                      // [0,16)
    const int hi = (slot >= 8) ? 1 : 0;
    const int b = xcd + 8 * hi;
    slot -= hi * 8;
    const int nt = (slot & 1) * 256, mt = (slot >> 1) * 256;
    ACC_INIT32(acc);
    gemm256_loop(expS + ((size_t)b * NSP + mt) * NSP,
                 Vb + ((size_t)b * CCH + nt) * NSP, NSP, NSP, NSP, L, acc);
    unsigned short* Ob = At + (size_t)b * NSP * CCH;
    const float* Ls = Lsum + (size_t)b * NSP;
    EPI256();
#pragma unroll
    for (int mi = 0; mi < 8; mi++) {
        const int row = mt + wr + mi * 16 + rr0;
#pragma unroll
        for (int r = 0; r < 4; r++) {
            const float inv = __builtin_amdgcn_rcpf(Ls[row + r]);
#pragma unroll
            for (int ni = 0; ni < 4; ni++) {
                const int col = nt + wc + ni * 16 + fr;
                Ob[(size_t)(row + r) * CCH + col] = f2bf(acc[mi * 4 + ni][r] * inv);
            }
        }
    }
}

// ---------------- proj: out = x + bp[o] + Wp[o][:] . At[n][:] ----------------
// grid: 128 blocks x 512 thr
__global__ __launch_bounds__(512, 2) void gemm_proj_k(
    const unsigned short* __restrict__ At, const unsigned short* __restrict__ wp,
    const float* __restrict__ bp, const float* __restrict__ x,
    float* __restrict__ out) {
    __shared__ __align__(16) short L[65536];
    const int lin = blockIdx.x, xcd = lin & 7;
    int slot = lin >> 3;                      // [0,16)
    const int hi = (slot >= 8) ? 1 : 0;
    const int b = xcd + 8 * hi;
    slot -= hi * 8;
    const int nt = (slot & 3) * 256, mt = (slot >> 2) * 256;
    ACC_INIT32(acc);
    gemm256_loop(wp + (size_t)mt * CCH, At + ((size_t)b * NSP + nt) * CCH,
                 CCH, CCH, CCH, L, acc);
    const size_t bbase = (size_t)b * CCH * NSP;
    EPI256();
#pragma unroll
    for (int mi = 0; mi < 8; mi++) {
        const int row = mt + wr + mi * 16 + rr0;
#pragma unroll
        for (int r = 0; r < 4; r++) {
            const float bias = bp[row + r];
#pragma unroll
            for (int ni = 0; ni < 4; ni++) {
                const int col = nt + wc + ni * 16 + fr;
                size_t idx = bbase + (size_t)(row + r) * NSP + col;
                out[idx] = x[idx] + bias + acc[mi * 4 + ni][r];
            }
        }
    }
}

extern "C" void kernel_launch(void* const* d_in, const int* in_sizes, int n_in,
                              void* d_out, int out_size, void* d_ws, size_t ws_size,
                              hipStream_t stream) {
    const float* x = (const float*)d_in[0];
    const float* gamma = (const float*)d_in[1];
    const float* beta = (const float*)d_in[2];
    const float* w_qkv = (const float*)d_in[3];
    const float* b_qkv = (const float*)d_in[4];
    const float* w_proj = (const float*)d_in[5];
    const float* b_proj = (const float*)d_in[6];
    float* out = (float*)d_out;

    char* ws = (char*)d_ws;
    const size_t MB = 1048576;
    unsigned short* wqkv_bf = (unsigned short*)ws;               // 1.5 MiB
    unsigned short* wproj_bf = (unsigned short*)(ws + 1572864);  // 0.5 MiB
    float* stats = (float*)(ws + 2 * MB);                        // 1 KiB
    float* Lsum = (float*)(ws + 2 * MB + 65536);                 // 64 KiB
    unsigned short* hn_t = (unsigned short*)(ws + 4 * MB);       // 16.8 MiB
    unsigned short* At = hn_t;                                   // aliases dead hn_t
    unsigned short* QKt = (unsigned short*)(ws + 24 * MB);       // 33.5 MiB
    unsigned short* Vb = (unsigned short*)(ws + 60 * MB);        // 16.8 MiB
    unsigned short* expS = (unsigned short*)(ws + 80 * MB);      // 33.5 MiB

    setup_k<<<1168, 256, 0, stream>>>(x, stats, w_qkv, wqkv_bf, 196608,
                                      w_proj, wproj_bf, 65536, Lsum);
    gn_tr_k<<<dim3(16, 8, BATCH), 256, 0, stream>>>(x, gamma, beta, stats, hn_t);
    gemm_qkv_k<<<384, 512, 0, stream>>>(hn_t, wqkv_bf, b_qkv, QKt, Vb);
    gemm_scores_k<<<256, 512, 0, stream>>>(QKt, expS, Lsum);
    gemm_pv_k<<<128, 512, 0, stream>>>(expS, Vb, Lsum, At);
    gemm_proj_k<<<128, 512, 0, stream>>>(At, wproj_bf, b_proj, x, out);
}

// Round 2
// 211.186 us; speedup vs baseline: 1.0470x; 1.0470x over previous
//
#include <hip/hip_runtime.h>

// Attention block: B=16, C=512, H=W=32 (N=1024), GROUPS=8, EPS=1e-5
// All GEMMs NT-form bf16 MFMA (A[M][K] x B[N][K]^T), 128x128 tiles,
// global_load_lds width-16 staging (m97 pattern).
//
// R8: REVERT of R7's 256^2 8-phase schedule (regressed 41->73us on qkv:
// 128KiB LDS -> 1 block/CU killed inter-block TLP; K=512 too short for the
// pipeline to reach steady state; vmcnt(4) stalls exposed ~400cy/phase).
// Back to R6's 2-phase 128^2 engine (5 blocks/CU, proven 209.8us total),
// PLUS the one mechanism R7 validated: bank-conflict swizzle. R6's frag
// reads stride 64B -> 8-way LDS bank conflict (3.1M/dispatch). Chunk-XOR
// (chunk ^= row&3) applied on the glds16 SOURCE address (dest must stay
// linear, m104/m173) and on the fragment READ offset cuts it to 4-way.
//
// Layouts: hn_t[B][N][C], QKt[B][N][1024]=[Q|K], V[B][C][N],
//          expS bf16 [B][N][N], At[B][N][C] (aliases dead hn_t).

#define BATCH 16
#define CCH 512
#define NSP 1024
#define EPSV 1e-5f
#define BK 32      // shorts per half-tile row
#define HT 4096    // shorts per half-tile (128*BK)

typedef short bf16x8 __attribute__((ext_vector_type(8)));
typedef float f32x4 __attribute__((ext_vector_type(4)));

__device__ __forceinline__ unsigned short f2bf(float f) {
    unsigned int u = __float_as_uint(f);
    u += 0x7FFF + ((u >> 16) & 1);  // RNE
    return (unsigned short)(u >> 16);
}

__device__ __forceinline__ void glds16(const void* g, void* l) {
    __builtin_amdgcn_global_load_lds(
        (const __attribute__((address_space(1))) unsigned int*)g,
        (__attribute__((address_space(3))) unsigned int*)l, 16, 0, 0);
}

// Decode 1-D block id -> (x, y, b) with batch pinned to XCD (lin%8).
#define XCD_MAP(GX_LOG2, PER, xv, yv, bv)                 \
    const int lin_ = blockIdx.x;                          \
    const int xcd_ = lin_ & 7;                            \
    int slot_ = lin_ >> 3;                                \
    const int hi_ = (slot_ >= (PER)) ? 1 : 0;             \
    const int bv = xcd_ + 8 * hi_;                        \
    slot_ -= hi_ * (PER);                                 \
    const int xv = slot_ & ((1 << (GX_LOG2)) - 1);        \
    const int yv = slot_ >> (GX_LOG2);

// ---------------- shared 128x128 NT mainloop, K=64 per barrier pair -------
// Al/Bl each 2*HT shorts (two K-half tiles, each [128][BK] packed).
// T2-lite swizzle: LDS slot (row, chunk c) holds global chunk c ^ (row&3);
// the glds16 source is pre-swizzled (dest stays linear), reads XOR back.
__device__ __forceinline__ void gemm128_loop(
    const unsigned short* __restrict__ Ag, const unsigned short* __restrict__ Bg,
    int astr, int bstr, int ktot, short* Al, short* Bl, f32x4* acc) {
    const int t = threadIdx.x;
    const int w = t >> 6, lane = t & 63;
    const int wr = (w >> 1) * 64, wc = (w & 1) * 64;
    const int fr = lane & 15;
    const int fsw = (((lane >> 4) ^ (fr & 3)) * 8);  // swizzled read chunk
    const int r0 = t >> 2;        // staging row (4 chunks/row)
    const int kc = (((t & 3) ^ (r0 & 3)) * 8);       // swizzled source chunk
    const unsigned short* Ap0 = Ag + (size_t)r0 * astr + kc;
    const unsigned short* Ap1 = Ag + (size_t)(r0 + 64) * astr + kc;
    const unsigned short* Bp0 = Bg + (size_t)r0 * bstr + kc;
    const unsigned short* Bp1 = Bg + (size_t)(r0 + 64) * bstr + kc;
    short* Alw = Al + w * 512;   // wave-uniform LDS base (lane*16B contiguous)
    short* Blw = Bl + w * 512;
    for (int k0 = 0; k0 < ktot; k0 += 64) {
        glds16(Ap0 + k0, Alw);
        glds16(Ap1 + k0, Alw + 2048);
        glds16(Ap0 + k0 + 32, Alw + HT);
        glds16(Ap1 + k0 + 32, Alw + HT + 2048);
        glds16(Bp0 + k0, Blw);
        glds16(Bp1 + k0, Blw + 2048);
        glds16(Bp0 + k0 + 32, Blw + HT);
        glds16(Bp1 + k0 + 32, Blw + HT + 2048);
        __syncthreads();
#pragma unroll
        for (int h = 0; h < 2; h++) {
            const short* Ab = Al + h * HT;
            const short* Bb = Bl + h * HT;
            bf16x8 af[4], bfr[4];
#pragma unroll
            for (int mi = 0; mi < 4; mi++)
                af[mi] = *(const bf16x8*)(Ab + (wr + mi * 16 + fr) * BK + fsw);
#pragma unroll
            for (int ni = 0; ni < 4; ni++)
                bfr[ni] = *(const bf16x8*)(Bb + (wc + ni * 16 + fr) * BK + fsw);
#pragma unroll
            for (int mi = 0; mi < 4; mi++)
#pragma unroll
                for (int ni = 0; ni < 4; ni++)
                    acc[mi * 4 + ni] = __builtin_amdgcn_mfma_f32_16x16x32_bf16(
                        af[mi], bfr[ni], acc[mi * 4 + ni], 0, 0, 0);
        }
        __syncthreads();
    }
}

#define EPI_SETUP()                                          \
    const int t = threadIdx.x, lane = t & 63, w = t >> 6;    \
    const int wr = (w >> 1) * 64, wc = (w & 1) * 64;         \
    const int fr = lane & 15, rr0 = (lane >> 4) * 4;

#define ACC_INIT(acc)                                        \
    f32x4 acc[16];                                           \
    _Pragma("unroll") for (int i = 0; i < 16; i++)           \
        acc[i] = (f32x4){0.f, 0.f, 0.f, 0.f};

// -- setup: GN stats (0..127) + weight cvt (128..1151) + Lsum zero (1152..) --
__global__ __launch_bounds__(256) void setup_k(
    const float* __restrict__ x, float* __restrict__ stats,
    const float* __restrict__ wa, unsigned short* __restrict__ oa, int na4,
    const float* __restrict__ wb, unsigned short* __restrict__ ob, int nb4,
    float* __restrict__ Lsum) {
    const int t = threadIdx.x;
    if (blockIdx.x < 128) {
        const int bg = blockIdx.x;
        const float4* xp = (const float4*)(x + (size_t)bg * 65536);
        float s = 0.f, q = 0.f;
#pragma unroll
        for (int i = 0; i < 64; i++) {
            float4 v = xp[t + i * 256];
            s += v.x + v.y + v.z + v.w;
            q += v.x * v.x + v.y * v.y + v.z * v.z + v.w * v.w;
        }
#pragma unroll
        for (int off = 32; off; off >>= 1) {
            s += __shfl_down(s, off);
            q += __shfl_down(q, off);
        }
        __shared__ float rs[4], rq[4];
        const int wave = t >> 6, lane = t & 63;
        if (lane == 0) { rs[wave] = s; rq[wave] = q; }
        __syncthreads();
        if (t == 0) {
            float S = rs[0] + rs[1] + rs[2] + rs[3];
            float Q = rq[0] + rq[1] + rq[2] + rq[3];
            const float inv = 1.f / 65536.f;
            float mean = S * inv;
            float var = Q * inv - mean * mean;
            stats[bg * 2] = mean;
            stats[bg * 2 + 1] = rsqrtf(var + EPSV);
        }
    } else if (blockIdx.x < 1152) {
        int i = (blockIdx.x - 128) * 256 + t;
        const float* src;
        unsigned short* dst;
        int j;
        if (i < na4) { src = wa; dst = oa; j = i; }
        else { j = i - na4; if (j >= nb4) return; src = wb; dst = ob; }
        float4 v = ((const float4*)src)[j];
        ushort4 o;
        o.x = f2bf(v.x); o.y = f2bf(v.y); o.z = f2bf(v.z); o.w = f2bf(v.w);
        ((ushort4*)dst)[j] = o;
    } else {
        int i = (blockIdx.x - 1152) * 256 + t;  // 16 blocks x 256 float4
        ((float4*)Lsum)[i] = (float4){0.f, 0.f, 0.f, 0.f};
    }
}

// ---------------- GN normalize + transpose -> hn_t[B][N][C] bf16 --------
__global__ __launch_bounds__(256) void gn_tr_k(
    const float* __restrict__ x, const float* __restrict__ gamma,
    const float* __restrict__ beta, const float* __restrict__ stats,
    unsigned short* __restrict__ hn_t) {
    const int nt = blockIdx.x, ct = blockIdx.y, b = blockIdx.z;
    __shared__ __align__(16) unsigned short T[64 * 72];  // [n][c] +pad
    const int t = threadIdx.x;
    const float mean = stats[(b * 8 + ct) * 2];
    const float rstd = stats[(b * 8 + ct) * 2 + 1];
    const int cl = t >> 2, nc = t & 3;
    const int c = ct * 64 + cl;
    const float ga = gamma[c] * rstd;
    const float be = beta[c] - mean * ga;
    const float4* xp = (const float4*)(x + ((size_t)b * CCH + c) * NSP + nt * 64);
#pragma unroll
    for (int j = 0; j < 4; j++) {
        float4 v = xp[nc * 4 + j];
        int n = nc * 16 + j * 4;
        T[(n + 0) * 72 + cl] = f2bf(v.x * ga + be);
        T[(n + 1) * 72 + cl] = f2bf(v.y * ga + be);
        T[(n + 2) * 72 + cl] = f2bf(v.z * ga + be);
        T[(n + 3) * 72 + cl] = f2bf(v.w * ga + be);
    }
    __syncthreads();
    const int nl = t >> 2, cc = t & 3;
    unsigned short* dst = hn_t + ((size_t)b * NSP + nt * 64 + nl) * CCH + ct * 64 + cc * 16;
    const unsigned short* src = T + nl * 72 + cc * 16;
    *(uint4*)dst = *(const uint4*)src;
    *(uint4*)(dst + 8) = *(const uint4*)(src + 8);
}

// ---------------- QKV (merged): y<8 -> Q|K rows, y>=8 -> V (transposed) ----
// grid: 1536 blocks, GX=8 (ntc), GY=12 (y), PER=96
__global__ __launch_bounds__(256) void gemm_qkv_k(
    const unsigned short* __restrict__ hn_t, const unsigned short* __restrict__ wq,
    const float* __restrict__ bq, unsigned short* __restrict__ QKt,
    unsigned short* __restrict__ Vb) {
    __shared__ __align__(16) short Al[2 * HT], Bl[2 * HT];
    XCD_MAP(3, 96, xb, y, b);
    const int ntc = xb * 128;
    ACC_INIT(acc);
    if (y < 8) {
        const int mt = y * 128;
        gemm128_loop(hn_t + ((size_t)b * NSP + mt) * CCH,
                     wq + (size_t)ntc * CCH, CCH, CCH, CCH, Al, Bl, acc);
        unsigned short* Ob = QKt + (size_t)b * NSP * 1024;
        EPI_SETUP();
#pragma unroll
        for (int ni = 0; ni < 4; ni++) {
            int col = ntc + wc + ni * 16 + fr;
            float bias = bq[col];
#pragma unroll
            for (int mi = 0; mi < 4; mi++) {
                int row = mt + wr + mi * 16 + rr0;
#pragma unroll
                for (int r = 0; r < 4; r++)
                    Ob[(size_t)(row + r) * 1024 + col] = f2bf(acc[mi * 4 + ni][r] + bias);
            }
        }
    } else {
        const int mt = (y - 8) * 128;
        gemm128_loop(wq + (size_t)(1024 + mt) * CCH,
                     hn_t + ((size_t)b * NSP + ntc) * CCH, CCH, CCH, CCH, Al, Bl, acc);
        unsigned short* Ob = Vb + (size_t)b * CCH * NSP;
        EPI_SETUP();
#pragma unroll
        for (int mi = 0; mi < 4; mi++) {
            int row = mt + wr + mi * 16 + rr0;
#pragma unroll
            for (int r = 0; r < 4; r++) {
                float bias = bq[1024 + row + r];
#pragma unroll
                for (int ni = 0; ni < 4; ni++) {
                    int col = ntc + wc + ni * 16 + fr;
                    Ob[(size_t)(row + r) * NSP + col] = f2bf(acc[mi * 4 + ni][r] + bias);
                }
            }
        }
    }
}

// ------- scores+exp: expS[b][n][m]=exp(scale*q.k) bf16; Lsum[b][n] += rowsum ----
// grid: 1024 blocks, GX=8 (nt), GY=8 (mt), PER=64
__global__ __launch_bounds__(256) void gemm_scores_k(
    const unsigned short* __restrict__ QKt, unsigned short* __restrict__ expS,
    float* __restrict__ Lsum) {
    __shared__ __align__(16) short Al[2 * HT], Bl[2 * HT];
    XCD_MAP(3, 64, xb, yb, b);
    const int nt = xb * 128, mt = yb * 128;
    const unsigned short* base = QKt + (size_t)b * NSP * 1024;
    ACC_INIT(acc);
    gemm128_loop(base + (size_t)mt * 1024, base + (size_t)nt * 1024 + 512,
                 1024, 1024, 512, Al, Bl, acc);
    unsigned short* Ob = expS + (size_t)b * NSP * NSP;
    float* Ls = Lsum + (size_t)b * NSP;
    const float scale = 0.044194173824159216f;  // 512^-0.5
    EPI_SETUP();
#pragma unroll
    for (int mi = 0; mi < 4; mi++) {
#pragma unroll
        for (int r = 0; r < 4; r++) {
            const int row = mt + wr + mi * 16 + rr0 + r;
            float rs = 0.f;
#pragma unroll
            for (int ni = 0; ni < 4; ni++) {
                int col = nt + wc + ni * 16 + fr;
                float e = __expf(acc[mi * 4 + ni][r] * scale);
                Ob[(size_t)row * NSP + col] = f2bf(e);
                rs += e;
            }
            rs += __shfl_xor(rs, 1);
            rs += __shfl_xor(rs, 2);
            rs += __shfl_xor(rs, 4);
            rs += __shfl_xor(rs, 8);
            if (fr == 0) atomicAdd(&Ls[row], rs);
        }
    }
}

// ---------------- PV: At[b][n][c] = (expS[n][:] . V[c][:]) / Lsum[n] --------
// grid: 512 blocks, GX=4 (ntc), GY=8 (mt), PER=32
__global__ __launch_bounds__(256) void gemm_pv_k(
    const unsigned short* __restrict__ expS, const unsigned short* __restrict__ Vb,
    const float* __restrict__ Lsum, unsigned short* __restrict__ At) {
    __shared__ __align__(16) short Al[2 * HT], Bl[2 * HT];
    XCD_MAP(2, 32, xb, yb, b);
    const int ntc = xb * 128, mt = yb * 128;
    ACC_INIT(acc);
    gemm128_loop(expS + ((size_t)b * NSP + mt) * NSP,
                 Vb + ((size_t)b * CCH + ntc) * NSP, NSP, NSP, NSP, Al, Bl, acc);
    unsigned short* Ob = At + (size_t)b * NSP * CCH;
    const float* Ls = Lsum + (size_t)b * NSP;
    EPI_SETUP();
#pragma unroll
    for (int mi = 0; mi < 4; mi++) {
        int row = mt + wr + mi * 16 + rr0;
#pragma unroll
        for (int r = 0; r < 4; r++) {
            float inv = __builtin_amdgcn_rcpf(Ls[row + r]);
#pragma unroll
            for (int ni = 0; ni < 4; ni++) {
                int col = ntc + wc + ni * 16 + fr;
                Ob[(size_t)(row + r) * CCH + col] = f2bf(acc[mi * 4 + ni][r] * inv);
            }
        }
    }
}

// ---------------- proj: out = x + bp[o] + Wp[o][:] . At[n][:] ----------------
// grid: 512 blocks, GX=8 (nt), GY=4 (mt), PER=32
__global__ __launch_bounds__(256) void gemm_proj_k(
    const unsigned short* __restrict__ At, const unsigned short* __restrict__ wp,
    const float* __restrict__ bp, const float* __restrict__ x,
    float* __restrict__ out) {
    __shared__ __align__(16) short Al[2 * HT], Bl[2 * HT];
    XCD_MAP(3, 32, xb, yb, b);
    const int nt = xb * 128, mt = yb * 128;
    ACC_INIT(acc);
    gemm128_loop(wp + (size_t)mt * CCH, At + ((size_t)b * NSP + nt) * CCH,
                 CCH, CCH, CCH, Al, Bl, acc);
    const size_t bbase = (size_t)b * CCH * NSP;
    EPI_SETUP();
#pragma unroll
    for (int mi = 0; mi < 4; mi++) {
        int row = mt + wr + mi * 16 + rr0;
#pragma unroll
        for (int r = 0; r < 4; r++) {
            float bias = bp[row + r];
#pragma unroll
            for (int ni = 0; ni < 4; ni++) {
                int col = nt + wc + ni * 16 + fr;
                size_t idx = bbase + (size_t)(row + r) * NSP + col;
                out[idx] = x[idx] + bias + acc[mi * 4 + ni][r];
            }
        }
    }
}

extern "C" void kernel_launch(void* const* d_in, const int* in_sizes, int n_in,
                              void* d_out, int out_size, void* d_ws, size_t ws_size,
                              hipStream_t stream) {
    const float* x = (const float*)d_in[0];
    const float* gamma = (const float*)d_in[1];
    const float* beta = (const float*)d_in[2];
    const float* w_qkv = (const float*)d_in[3];
    const float* b_qkv = (const float*)d_in[4];
    const float* w_proj = (const float*)d_in[5];
    const float* b_proj = (const float*)d_in[6];
    float* out = (float*)d_out;

    char* ws = (char*)d_ws;
    const size_t MB = 1048576;
    unsigned short* wqkv_bf = (unsigned short*)ws;               // 1.5 MiB
    unsigned short* wproj_bf = (unsigned short*)(ws + 1572864);  // 0.5 MiB
    float* stats = (float*)(ws + 2 * MB);                        // 1 KiB
    float* Lsum = (float*)(ws + 2 * MB + 65536);                 // 64 KiB
    unsigned short* hn_t = (unsigned short*)(ws + 4 * MB);       // 16.8 MiB
    unsigned short* At = hn_t;                                   // aliases dead hn_t
    unsigned short* QKt = (unsigned short*)(ws + 24 * MB);       // 33.5 MiB
    unsigned short* Vb = (unsigned short*)(ws + 60 * MB);        // 16.8 MiB
    unsigned short* expS = (unsigned short*)(ws + 80 * MB);      // 33.5 MiB

    setup_k<<<1168, 256, 0, stream>>>(x, stats, w_qkv, wqkv_bf, 196608,
                                      w_proj, wproj_bf, 65536, Lsum);
    gn_tr_k<<<dim3(16, 8, BATCH), 256, 0, stream>>>(x, gamma, beta, stats, hn_t);
    gemm_qkv_k<<<1536, 256, 0, stream>>>(hn_t, wqkv_bf, b_qkv, QKt, Vb);
    gemm_scores_k<<<1024, 256, 0, stream>>>(QKt, expS, Lsum);
    gemm_pv_k<<<512, 256, 0, stream>>>(expS, Vb, Lsum, At);
    gemm_proj_k<<<512, 256, 0, stream>>>(At, wproj_bf, b_proj, x, out);
}